// Round 19
// baseline (61.774 us; speedup 1.0000x reference)
//
#include <hip/hip_runtime.h>
#include <hip/hip_bf16.h>

typedef __attribute__((ext_vector_type(8))) short bf16x8;
typedef __attribute__((ext_vector_type(4))) float f32x4;
typedef __attribute__((ext_vector_type(4))) unsigned short u16x4;

#define MFMA16(a, b, c) __builtin_amdgcn_mfma_f32_16x16x32_bf16(a, b, c, 0, 0, 0)

// B=16, S=2048, EMB=512, HEAD_DIM=64
// Q pre-scaled by 0.125 * log2(e): softmax runs in exp2 domain.
#define QSCALE 0.18033688011112042f

#define GLDS16(gp, lp)                                                         \
    __builtin_amdgcn_global_load_lds(                                          \
        (const __attribute__((address_space(1))) void*)(gp),                   \
        (__attribute__((address_space(3))) void*)(lp), 16, 0, 0)

__device__ __forceinline__ short nbf(float f) {
    __hip_bfloat16 h = __float2bfloat16(f);
    return *(short*)&h;
}
__device__ __forceinline__ unsigned short nbfu(float f) {
    __hip_bfloat16 h = __float2bfloat16(f);
    return *(unsigned short*)&h;
}

__global__ void wt_kernel(const float* __restrict__ Wq, const float* __restrict__ Wk,
                          const float* __restrict__ Wv, unsigned short* __restrict__ Wt) {
    const int h = blockIdx.x;
    const int mat = blockIdx.y;
    const int e = threadIdx.x;
    const float* W = (mat == 0) ? Wq : ((mat == 1) ? Wk : Wv);
    Wt[(mat * 64 + h) * 512 + e] = nbfu(W[e * 64 + h]);
}

// Fused QKV projection v5 (R17 verbatim — R18's counted-vmcnt was null; qkv
// is near its pipe floor): writes fragment-tiled Kf/Vf.
__global__ __launch_bounds__(512, 1) void qkv_proj(
    const float* __restrict__ x1, const unsigned short* __restrict__ Wt,
    unsigned short* __restrict__ Q, unsigned short* __restrict__ Kf,
    unsigned short* __restrict__ Vf)
{
    __shared__ char alds[2][16384];
    __shared__ char blds[2][12288];

    const int tid = threadIdx.x;
    const int W = tid >> 6, lane = tid & 63;
    const int c = lane & 15, g = lane >> 4;
    const int tokB = blockIdx.x * 128;

    const char* x1b = (const char*)x1;
    const char* Wtb = (const char*)Wt;

    const int tA0 = tid >> 3,           qA0 = (tid & 7) ^ (tA0 & 7);
    const int tA1 = (tid + 512) >> 3,   qA1 = (tid & 7) ^ (tA1 & 7);
    const size_t aoff0 = (size_t)(tokB + tA0) * 2048 + qA0 * 16;
    const size_t aoff1 = (size_t)(tokB + tA1) * 2048 + qA1 * 16;

    auto bsrc = [&](int j) -> size_t {
        const int n = j >> 6, c2 = (j >> 2) & 15, g2 = j & 3;
        return (size_t)((n >> 2) * 64 + (n & 3) * 16 + c2) * 1024 + g2 * 16;
    };
    const size_t boff0 = bsrc(tid), boff1 = bsrc(tid + 512);

    f32x4 acc[12];
#pragma unroll
    for (int n = 0; n < 12; ++n) acc[n] = (f32x4)0.f;

    GLDS16(x1b + aoff0, &alds[0][tid * 16]);
    GLDS16(x1b + aoff1, &alds[0][8192 + tid * 16]);
    GLDS16(Wtb + boff0, &blds[0][tid * 16]);
    if (tid < 256) GLDS16(Wtb + boff1, &blds[0][8192 + tid * 16]);

    const int arow = (W * 16 + c) * 128;
    const int aq0 = (((2 * g) ^ (c & 7)) * 16);
    const int aq1 = (((2 * g + 1) ^ (c & 7)) * 16);
    const int brd = (c * 4 + g) * 16;

    int buf = 0;
    for (int ks = 0; ks < 16; ++ks) {
        asm volatile("s_waitcnt vmcnt(0)\n\ts_barrier" ::: "memory");

        if (ks < 15) {
            const size_t ka = (size_t)(ks + 1) * 128;
            const size_t kb = (size_t)(ks + 1) * 64;
            char* ab = &alds[buf ^ 1][0];
            char* bb = &blds[buf ^ 1][0];
            GLDS16(x1b + aoff0 + ka, ab + tid * 16);
            GLDS16(x1b + aoff1 + ka, ab + 8192 + tid * 16);
            GLDS16(Wtb + boff0 + kb, bb + tid * 16);
            if (tid < 256) GLDS16(Wtb + boff1 + kb, bb + 8192 + tid * 16);
        }

        const char* ab = &alds[buf][0];
        const char* bb = &blds[buf][0];
        f32x4 a0 = *(const f32x4*)(ab + arow + aq0);
        f32x4 a1 = *(const f32x4*)(ab + arow + aq1);
        bf16x8 af;
        af[0] = nbf(a0[0]); af[1] = nbf(a0[1]); af[2] = nbf(a0[2]); af[3] = nbf(a0[3]);
        af[4] = nbf(a1[0]); af[5] = nbf(a1[1]); af[6] = nbf(a1[2]); af[7] = nbf(a1[3]);
#pragma unroll
        for (int n = 0; n < 12; ++n) {
            bf16x8 bf = *(const bf16x8*)(bb + n * 1024 + brd);
            acc[n] = MFMA16(af, bf, acc[n]);
        }
        buf ^= 1;
    }

    const int tok0 = tokB + W * 16;
    const int bb2 = tokB >> 11;
    const int ht = ((tokB & 2047) >> 6) + (W >> 2);

#pragma unroll
    for (int n = 0; n < 4; ++n)
#pragma unroll
        for (int r = 0; r < 4; ++r)
            Q[(size_t)(tok0 + g * 4 + r) * 64 + n * 16 + c] = nbfu(acc[n][r] * QSCALE);

    {
        unsigned short* kf = Kf + (size_t)bb2 * 131072 + (size_t)ht * 4096;
#pragma unroll
        for (int n = 0; n < 4; ++n) {
            const int gf = (n & 1) * 2 + (c >> 3);
            const size_t base = (size_t)(n >> 1) * 2048 + (W & 3) * 512 + (c & 7);
#pragma unroll
            for (int r = 0; r < 4; ++r)
                kf[base + (size_t)(gf * 16 + g * 4 + r) * 8] = nbfu(acc[4 + n][r]);
        }
    }

    {
        unsigned short* vf = Vf + (size_t)bb2 * 131072 + (size_t)ht * 4096;
        const int sub = (W & 3) >> 1;
        const int gf = (W & 1) * 2 + (g >> 1);
        const int jb = (g & 1) * 4;
#pragma unroll
        for (int n = 0; n < 4; ++n) {
            u16x4 pv;
#pragma unroll
            for (int r = 0; r < 4; ++r) pv[r] = nbfu(acc[8 + n][r]);
            *(u16x4*)(vf + (size_t)sub * 2048 + n * 512 + (gf * 16 + c) * 8 + jb) = pv;
        }
    }
}

// Causal flash attention v14: 32 q-rows per wave (2 x 16-row fragments A/B
// sharing every K/V fragment load) + 4-way key-split.
//  - halves K/V L2 traffic and per-wave fragment ops per unit work vs v13.
//  - 8 waves = 2 q-groups (qg=W>>2, 32 rows) x 4 key-sets (st=W&3, t += 4).
//  - per-fragment softmax/P machinery byte-identical to v13 within each 4KB
//    P region; epilogue = guarded 4-way flash combine.
__global__ __launch_bounds__(512, 2) void flash_attn(
    const unsigned short* __restrict__ Q, const unsigned short* __restrict__ Kf,
    const unsigned short* __restrict__ Vf, float* __restrict__ out)
{
    __shared__ char p_lds[65536];        // [wave 0..7][ fragA 4KB | fragB 4KB ]; reused for merge
    __shared__ float mlb[2][2][3][32];   // [m|l][qg][st-1][row 0..31]

    const int tid = threadIdx.x;
    const int W = tid >> 6;
    const int st = W & 3;          // key-set
    const int qg = W >> 2;         // q-group (32 rows each)
    const int lane = tid & 63;
    const int c = lane & 15, g = lane >> 4;

    const int id = blockIdx.x;
    const int b = 2 * (id & 7) + ((id >> 3) & 1);
    const int k = id >> 4;                         // 0..31
    const int qt = (k < 16) ? (31 - k) : (k - 16); // pair (k,k+16): qt sum = 31
    const int n2 = (qt >> 1) + 1;                  // # 128-key tiles
    const int qrA = qt * 64 + qg * 32 + c;         // fragA lane q-row
    const int qrB = qrA + 16;                      // fragB lane q-row
    const size_t qbase = ((size_t)b << 11) + qt * 64 + qg * 32;

    bf16x8 qfA0 = *(const bf16x8*)(Q + (qbase + c) * 64 + g * 8);
    bf16x8 qfA1 = *(const bf16x8*)(Q + (qbase + c) * 64 + 32 + g * 8);
    bf16x8 qfB0 = *(const bf16x8*)(Q + (qbase + 16 + c) * 64 + g * 8);
    bf16x8 qfB1 = *(const bf16x8*)(Q + (qbase + 16 + c) * 64 + 32 + g * 8);

    const char* Kfb = (const char*)(Kf + (size_t)b * 131072);
    const char* Vfb = (const char*)(Vf + (size_t)b * 131072);

    float mA = -1e30f, lA = 0.f;
    float mB = -1e30f, lB = 0.f;
    f32x4 accA[4], accB[4];
#pragma unroll
    for (int n = 0; n < 4; ++n) { accA[n] = (f32x4)0.f; accB[n] = (f32x4)0.f; }

    for (int t = st; t < n2; t += 4) {
        const char* kt = Kfb + (size_t)t * 16384;
        const char* vt = Vfb + (size_t)t * 16384;

        // ---- S^T = K Q^T for both q-fragments; K fragments loaded ONCE ----
        f32x4 sA[8], sB[8];
#pragma unroll
        for (int i = 0; i < 8; ++i) { sA[i] = (f32x4)0.f; sB[i] = (f32x4)0.f; }
#pragma unroll
        for (int h = 0; h < 2; ++h) {
            bf16x8 ka[4], kb2[4];
#pragma unroll
            for (int n = 0; n < 4; ++n) {
                ka[n]  = *(const bf16x8*)(kt + h * 8192 + n * 1024 + lane * 16);
                kb2[n] = *(const bf16x8*)(kt + h * 8192 + 4096 + n * 1024 + lane * 16);
            }
            __builtin_amdgcn_s_setprio(1);
#pragma unroll
            for (int n = 0; n < 4; ++n) {
                sA[h * 4 + n] = MFMA16(ka[n], qfA0, sA[h * 4 + n]);
                sA[h * 4 + n] = MFMA16(kb2[n], qfA1, sA[h * 4 + n]);
                sB[h * 4 + n] = MFMA16(ka[n], qfB0, sB[h * 4 + n]);
                sB[h * 4 + n] = MFMA16(kb2[n], qfB1, sB[h * 4 + n]);
            }
            __builtin_amdgcn_s_setprio(0);
        }

        // ---- causal mask (diagonal tile only) ----
        if (t == n2 - 1) {
#pragma unroll
            for (int h = 0; h < 2; ++h)
#pragma unroll
                for (int n = 0; n < 4; ++n) {
                    const int key0 = t * 128 + h * 64 + n * 16 + g * 4;
#pragma unroll
                    for (int r = 0; r < 4; ++r) {
                        if (key0 + r > qrA) sA[h * 4 + n][r] = -1e30f;
                        if (key0 + r > qrB) sB[h * 4 + n][r] = -1e30f;
                    }
                }
        }

        // ================= fragment A softmax + P write =================
        {
            float tm = -1e30f;
#pragma unroll
            for (int i = 0; i < 8; ++i)
                tm = fmaxf(tm, fmaxf(fmaxf(sA[i][0], sA[i][1]), fmaxf(sA[i][2], sA[i][3])));
            if (__any(tm > mA + 8.f)) {
                float gm = tm;
                gm = fmaxf(gm, __shfl_xor(gm, 16, 64));
                gm = fmaxf(gm, __shfl_xor(gm, 32, 64));
                const float mn = fmaxf(mA, gm);
                const float alpha = exp2f(mA - mn);
                mA = mn;
                lA *= alpha;
                float al[4];
#pragma unroll
                for (int r = 0; r < 4; ++r) al[r] = __shfl(alpha, g * 4 + r, 16);
#pragma unroll
                for (int n = 0; n < 4; ++n)
#pragma unroll
                    for (int r = 0; r < 4; ++r) accA[n][r] *= al[r];
            }
            char* pw = &p_lds[W * 8192 + ((g >> 1) * 16 + c) * 16 + (g & 1) * 8];
#pragma unroll
            for (int h = 0; h < 2; ++h)
#pragma unroll
                for (int n = 0; n < 4; ++n) {
                    const int i = h * 4 + n;
                    float p0 = exp2f(sA[i][0] - mA);
                    float p1 = exp2f(sA[i][1] - mA);
                    float p2 = exp2f(sA[i][2] - mA);
                    float p3 = exp2f(sA[i][3] - mA);
                    lA += (p0 + p1) + (p2 + p3);
                    u16x4 pk;
                    pk[0] = nbfu(p0); pk[1] = nbfu(p1); pk[2] = nbfu(p2); pk[3] = nbfu(p3);
                    *(u16x4*)(pw + (h * 2 + (n >> 1)) * 1024 + (n & 1) * 512) = pk;
                }
        }
        // ================= fragment B softmax + P write =================
        {
            float tm = -1e30f;
#pragma unroll
            for (int i = 0; i < 8; ++i)
                tm = fmaxf(tm, fmaxf(fmaxf(sB[i][0], sB[i][1]), fmaxf(sB[i][2], sB[i][3])));
            if (__any(tm > mB + 8.f)) {
                float gm = tm;
                gm = fmaxf(gm, __shfl_xor(gm, 16, 64));
                gm = fmaxf(gm, __shfl_xor(gm, 32, 64));
                const float mn = fmaxf(mB, gm);
                const float alpha = exp2f(mB - mn);
                mB = mn;
                lB *= alpha;
                float al[4];
#pragma unroll
                for (int r = 0; r < 4; ++r) al[r] = __shfl(alpha, g * 4 + r, 16);
#pragma unroll
                for (int n = 0; n < 4; ++n)
#pragma unroll
                    for (int r = 0; r < 4; ++r) accB[n][r] *= al[r];
            }
            char* pw = &p_lds[W * 8192 + 4096 + ((g >> 1) * 16 + c) * 16 + (g & 1) * 8];
#pragma unroll
            for (int h = 0; h < 2; ++h)
#pragma unroll
                for (int n = 0; n < 4; ++n) {
                    const int i = h * 4 + n;
                    float p0 = exp2f(sB[i][0] - mB);
                    float p1 = exp2f(sB[i][1] - mB);
                    float p2 = exp2f(sB[i][2] - mB);
                    float p3 = exp2f(sB[i][3] - mB);
                    lB += (p0 + p1) + (p2 + p3);
                    u16x4 pk;
                    pk[0] = nbfu(p0); pk[1] = nbfu(p1); pk[2] = nbfu(p2); pk[3] = nbfu(p3);
                    *(u16x4*)(pw + (h * 2 + (n >> 1)) * 1024 + (n & 1) * 512) = pk;
                }
        }

        // ---- O += P V : V fragments loaded ONCE, used by both fragments ----
        const char* prA = &p_lds[W * 8192 + lane * 16];
        const char* prB = prA + 4096;
#pragma unroll
        for (int ps = 0; ps < 4; ++ps) {
            bf16x8 pfA = *(const bf16x8*)(prA + ps * 1024);
            bf16x8 pfB = *(const bf16x8*)(prB + ps * 1024);
            bf16x8 vf[4];
#pragma unroll
            for (int n = 0; n < 4; ++n)
                vf[n] = *(const bf16x8*)(vt + (ps >> 1) * 8192 + (ps & 1) * 4096 + n * 1024 + lane * 16);
            __builtin_amdgcn_s_setprio(1);
#pragma unroll
            for (int n = 0; n < 4; ++n) {
                accA[n] = MFMA16(pfA, vf[n], accA[n]);
                accB[n] = MFMA16(pfB, vf[n], accB[n]);
            }
            __builtin_amdgcn_s_setprio(0);
        }
    }

    // ---- epilogue: guarded 4-way merge per q-group ----
    lA += __shfl_xor(lA, 16, 64); lA += __shfl_xor(lA, 32, 64);
    lB += __shfl_xor(lB, 16, 64); lB += __shfl_xor(lB, 32, 64);
    __syncthreads();
    float* accb = (float*)&p_lds[0];   // [slot=(st-1)*2+qg][32 rows][64 cols] f32 = 48KB

    if (st != 0) {
        const int slot = (st - 1) * 2 + qg;
        if (g == 0) {
            mlb[0][qg][st - 1][c] = mA;      mlb[0][qg][st - 1][16 + c] = mB;
            mlb[1][qg][st - 1][c] = lA;      mlb[1][qg][st - 1][16 + c] = lB;
        }
#pragma unroll
        for (int n = 0; n < 4; ++n)
#pragma unroll
            for (int r = 0; r < 4; ++r) {
                accb[slot * 2048 + (g * 4 + r) * 64 + n * 16 + c] = accA[n][r];
                accb[slot * 2048 + (16 + g * 4 + r) * 64 + n * 16 + c] = accB[n][r];
            }
    }
    __syncthreads();

    if (st == 0) {
        // ---- fragment A rows (qbase + 0..15) ----
        {
            const float m1 = mlb[0][qg][0][c], l1 = mlb[1][qg][0][c];
            const float m2 = mlb[0][qg][1][c], l2 = mlb[1][qg][1][c];
            const float m3 = mlb[0][qg][2][c], l3 = mlb[1][qg][2][c];
            const float mF = fmaxf(fmaxf(mA, m1), fmaxf(m2, m3));
            const float a0 = exp2f(mA - mF);
            const float a1 = (m1 > -1e29f) ? exp2f(m1 - mF) : 0.f;
            const float a2 = (m2 > -1e29f) ? exp2f(m2 - mF) : 0.f;
            const float a3 = (m3 > -1e29f) ? exp2f(m3 - mF) : 0.f;
            const float inv = 1.f / (lA * a0 + l1 * a1 + l2 * a2 + l3 * a3);
            const float s0 = a0 * inv, s1 = a1 * inv, s2 = a2 * inv, s3 = a3 * inv;
            float s0r[4], s1r[4], s2r[4], s3r[4];
#pragma unroll
            for (int r = 0; r < 4; ++r) {
                s0r[r] = __shfl(s0, g * 4 + r, 16);
                s1r[r] = __shfl(s1, g * 4 + r, 16);
                s2r[r] = __shfl(s2, g * 4 + r, 16);
                s3r[r] = __shfl(s3, g * 4 + r, 16);
            }
#pragma unroll
            for (int n = 0; n < 4; ++n)
#pragma unroll
                for (int r = 0; r < 4; ++r) {
                    const int ro = (g * 4 + r) * 64 + n * 16 + c;
                    const float v = accA[n][r] * s0r[r]
                                  + accb[(0 * 2 + qg) * 2048 + ro] * s1r[r]
                                  + accb[(1 * 2 + qg) * 2048 + ro] * s2r[r]
                                  + accb[(2 * 2 + qg) * 2048 + ro] * s3r[r];
                    out[(qbase + g * 4 + r) * 64 + n * 16 + c] = v;
                }
        }
        // ---- fragment B rows (qbase + 16..31) ----
        {
            const float m1 = mlb[0][qg][0][16 + c], l1 = mlb[1][qg][0][16 + c];
            const float m2 = mlb[0][qg][1][16 + c], l2 = mlb[1][qg][1][16 + c];
            const float m3 = mlb[0][qg][2][16 + c], l3 = mlb[1][qg][2][16 + c];
            const float mF = fmaxf(fmaxf(mB, m1), fmaxf(m2, m3));
            const float a0 = exp2f(mB - mF);
            const float a1 = (m1 > -1e29f) ? exp2f(m1 - mF) : 0.f;
            const float a2 = (m2 > -1e29f) ? exp2f(m2 - mF) : 0.f;
            const float a3 = (m3 > -1e29f) ? exp2f(m3 - mF) : 0.f;
            const float inv = 1.f / (lB * a0 + l1 * a1 + l2 * a2 + l3 * a3);
            const float s0 = a0 * inv, s1 = a1 * inv, s2 = a2 * inv, s3 = a3 * inv;
            float s0r[4], s1r[4], s2r[4], s3r[4];
#pragma unroll
            for (int r = 0; r < 4; ++r) {
                s0r[r] = __shfl(s0, g * 4 + r, 16);
                s1r[r] = __shfl(s1, g * 4 + r, 16);
                s2r[r] = __shfl(s2, g * 4 + r, 16);
                s3r[r] = __shfl(s3, g * 4 + r, 16);
            }
#pragma unroll
            for (int n = 0; n < 4; ++n)
#pragma unroll
                for (int r = 0; r < 4; ++r) {
                    const int ro = (16 + g * 4 + r) * 64 + n * 16 + c;
                    const float v = accB[n][r] * s0r[r]
                                  + accb[(0 * 2 + qg) * 2048 + ro] * s1r[r]
                                  + accb[(1 * 2 + qg) * 2048 + ro] * s2r[r]
                                  + accb[(2 * 2 + qg) * 2048 + ro] * s3r[r];
                    out[(qbase + 16 + g * 4 + r) * 64 + n * 16 + c] = v;
                }
        }
    }
}

extern "C" void kernel_launch(void* const* d_in, const int* in_sizes, int n_in,
                              void* d_out, int out_size, void* d_ws, size_t ws_size,
                              hipStream_t stream) {
    const float* x1 = (const float*)d_in[0];
    const float* Wq = (const float*)d_in[2];
    const float* Wk = (const float*)d_in[3];
    const float* Wv = (const float*)d_in[4];
    float* out = (float*)d_out;

    unsigned short* Wt  = (unsigned short*)d_ws;
    unsigned short* Qw  = (unsigned short*)((char*)d_ws + 196608);
    unsigned short* Kfw = (unsigned short*)((char*)d_ws + 196608 + 4194304);
    unsigned short* Vfw = (unsigned short*)((char*)d_ws + 196608 + 2 * 4194304);

    wt_kernel<<<dim3(64, 3), 512, 0, stream>>>(Wq, Wk, Wv, Wt);
    qkv_proj<<<256, 512, 0, stream>>>(x1, Wt, Qw, Kfw, Vfw);
    flash_attn<<<512, 512, 0, stream>>>(Qw, Kfw, Vfw, out);
}

// Round 20
// 54.063 us; speedup vs baseline: 1.1426x; 1.1426x over previous
//
#include <hip/hip_runtime.h>
#include <hip/hip_bf16.h>

typedef __attribute__((ext_vector_type(8))) short bf16x8;
typedef __attribute__((ext_vector_type(4))) float f32x4;
typedef __attribute__((ext_vector_type(4))) unsigned short u16x4;

#define MFMA16(a, b, c) __builtin_amdgcn_mfma_f32_16x16x32_bf16(a, b, c, 0, 0, 0)

// B=16, S=2048, EMB=512, HEAD_DIM=64
// Q pre-scaled by 0.125 * log2(e): softmax runs in exp2 domain.
#define QSCALE 0.18033688011112042f

#define GLDS16(gp, lp)                                                         \
    __builtin_amdgcn_global_load_lds(                                          \
        (const __attribute__((address_space(1))) void*)(gp),                   \
        (__attribute__((address_space(3))) void*)(lp), 16, 0, 0)

__device__ __forceinline__ short nbf(float f) {
    __hip_bfloat16 h = __float2bfloat16(f);
    return *(short*)&h;
}
__device__ __forceinline__ unsigned short nbfu(float f) {
    __hip_bfloat16 h = __float2bfloat16(f);
    return *(unsigned short*)&h;
}

__global__ void wt_kernel(const float* __restrict__ Wq, const float* __restrict__ Wk,
                          const float* __restrict__ Wv, unsigned short* __restrict__ Wt) {
    const int h = blockIdx.x;
    const int mat = blockIdx.y;
    const int e = threadIdx.x;
    const float* W = (mat == 0) ? Wq : ((mat == 1) ? Wk : Wv);
    Wt[(mat * 64 + h) * 512 + e] = nbfu(W[e * 64 + h]);
}

// Fused QKV projection v5 (R17 verbatim): writes fragment-tiled Kf/Vf.
__global__ __launch_bounds__(512, 1) void qkv_proj(
    const float* __restrict__ x1, const unsigned short* __restrict__ Wt,
    unsigned short* __restrict__ Q, unsigned short* __restrict__ Kf,
    unsigned short* __restrict__ Vf)
{
    __shared__ char alds[2][16384];
    __shared__ char blds[2][12288];

    const int tid = threadIdx.x;
    const int W = tid >> 6, lane = tid & 63;
    const int c = lane & 15, g = lane >> 4;
    const int tokB = blockIdx.x * 128;

    const char* x1b = (const char*)x1;
    const char* Wtb = (const char*)Wt;

    const int tA0 = tid >> 3,           qA0 = (tid & 7) ^ (tA0 & 7);
    const int tA1 = (tid + 512) >> 3,   qA1 = (tid & 7) ^ (tA1 & 7);
    const size_t aoff0 = (size_t)(tokB + tA0) * 2048 + qA0 * 16;
    const size_t aoff1 = (size_t)(tokB + tA1) * 2048 + qA1 * 16;

    auto bsrc = [&](int j) -> size_t {
        const int n = j >> 6, c2 = (j >> 2) & 15, g2 = j & 3;
        return (size_t)((n >> 2) * 64 + (n & 3) * 16 + c2) * 1024 + g2 * 16;
    };
    const size_t boff0 = bsrc(tid), boff1 = bsrc(tid + 512);

    f32x4 acc[12];
#pragma unroll
    for (int n = 0; n < 12; ++n) acc[n] = (f32x4)0.f;

    GLDS16(x1b + aoff0, &alds[0][tid * 16]);
    GLDS16(x1b + aoff1, &alds[0][8192 + tid * 16]);
    GLDS16(Wtb + boff0, &blds[0][tid * 16]);
    if (tid < 256) GLDS16(Wtb + boff1, &blds[0][8192 + tid * 16]);

    const int arow = (W * 16 + c) * 128;
    const int aq0 = (((2 * g) ^ (c & 7)) * 16);
    const int aq1 = (((2 * g + 1) ^ (c & 7)) * 16);
    const int brd = (c * 4 + g) * 16;

    int buf = 0;
    for (int ks = 0; ks < 16; ++ks) {
        asm volatile("s_waitcnt vmcnt(0)\n\ts_barrier" ::: "memory");

        if (ks < 15) {
            const size_t ka = (size_t)(ks + 1) * 128;
            const size_t kb = (size_t)(ks + 1) * 64;
            char* ab = &alds[buf ^ 1][0];
            char* bb = &blds[buf ^ 1][0];
            GLDS16(x1b + aoff0 + ka, ab + tid * 16);
            GLDS16(x1b + aoff1 + ka, ab + 8192 + tid * 16);
            GLDS16(Wtb + boff0 + kb, bb + tid * 16);
            if (tid < 256) GLDS16(Wtb + boff1 + kb, bb + 8192 + tid * 16);
        }

        const char* ab = &alds[buf][0];
        const char* bb = &blds[buf][0];
        f32x4 a0 = *(const f32x4*)(ab + arow + aq0);
        f32x4 a1 = *(const f32x4*)(ab + arow + aq1);
        bf16x8 af;
        af[0] = nbf(a0[0]); af[1] = nbf(a0[1]); af[2] = nbf(a0[2]); af[3] = nbf(a0[3]);
        af[4] = nbf(a1[0]); af[5] = nbf(a1[1]); af[6] = nbf(a1[2]); af[7] = nbf(a1[3]);
#pragma unroll
        for (int n = 0; n < 12; ++n) {
            bf16x8 bf = *(const bf16x8*)(bb + n * 1024 + brd);
            acc[n] = MFMA16(af, bf, acc[n]);
        }
        buf ^= 1;
    }

    const int tok0 = tokB + W * 16;
    const int bb2 = tokB >> 11;
    const int ht = ((tokB & 2047) >> 6) + (W >> 2);

#pragma unroll
    for (int n = 0; n < 4; ++n)
#pragma unroll
        for (int r = 0; r < 4; ++r)
            Q[(size_t)(tok0 + g * 4 + r) * 64 + n * 16 + c] = nbfu(acc[n][r] * QSCALE);

    {
        unsigned short* kf = Kf + (size_t)bb2 * 131072 + (size_t)ht * 4096;
#pragma unroll
        for (int n = 0; n < 4; ++n) {
            const int gf = (n & 1) * 2 + (c >> 3);
            const size_t base = (size_t)(n >> 1) * 2048 + (W & 3) * 512 + (c & 7);
#pragma unroll
            for (int r = 0; r < 4; ++r)
                kf[base + (size_t)(gf * 16 + g * 4 + r) * 8] = nbfu(acc[4 + n][r]);
        }
    }

    {
        unsigned short* vf = Vf + (size_t)bb2 * 131072 + (size_t)ht * 4096;
        const int sub = (W & 3) >> 1;
        const int gf = (W & 1) * 2 + (g >> 1);
        const int jb = (g & 1) * 4;
#pragma unroll
        for (int n = 0; n < 4; ++n) {
            u16x4 pv;
#pragma unroll
            for (int r = 0; r < 4; ++r) pv[r] = nbfu(acc[8 + n][r]);
            *(u16x4*)(vf + (size_t)sub * 2048 + n * 512 + (gf * 16 + c) * 8 + jb) = pv;
        }
    }
}

// Causal flash attention v13b: R17's v13 + V ps=0,1 fragments hoisted before
// softmax (8 loads, +32 VGPR, still within the 128-VGPR (512,4) budget) so
// softmax VALU covers their L2 latency; ps=2,3 loaded in place (covered by
// the ps=0,1 MFMAs).
__global__ __launch_bounds__(512, 4) void flash_attn(
    const unsigned short* __restrict__ Q, const unsigned short* __restrict__ Kf,
    const unsigned short* __restrict__ Vf, float* __restrict__ out)
{
    __shared__ char p_lds[32768];   // [wave 0..7][ps=4][lane=64]x16B; reused for merge
    __shared__ float mb[4][16], lb[4][16];

    const int tid = threadIdx.x;
    const int W = tid >> 6;
    const int st = W >> 2;
    const int w = W & 3;
    const int lane = tid & 63;
    const int c = lane & 15, g = lane >> 4;

    const int id = blockIdx.x;
    const int b = 2 * (id & 7) + ((id >> 3) & 1);
    const int k = id >> 4;                         // 0..31
    const int qt = (k < 16) ? (31 - k) : (k - 16); // pair (k,k+16): qt sum = 31
    const int n2 = (qt >> 1) + 1;                  // # 128-key tiles
    const int qr0c = qt * 64 + w * 16 + c;
    const size_t qrow_g = ((size_t)b << 11) + qt * 64 + w * 16;

    bf16x8 qf0 = *(const bf16x8*)(Q + (qrow_g + c) * 64 + g * 8);
    bf16x8 qf1 = *(const bf16x8*)(Q + (qrow_g + c) * 64 + 32 + g * 8);

    const char* Kfb = (const char*)(Kf + (size_t)b * 131072);
    const char* Vfb = (const char*)(Vf + (size_t)b * 131072);

    float m = -1e30f, l = 0.f;
    f32x4 acc[4];
#pragma unroll
    for (int n = 0; n < 4; ++n) acc[n] = (f32x4)0.f;

    for (int t = st; t < n2; t += 2) {
        const char* kt = Kfb + (size_t)t * 16384;
        const char* vt = Vfb + (size_t)t * 16384;

        f32x4 s[8];
#pragma unroll
        for (int i = 0; i < 8; ++i) s[i] = (f32x4)0.f;
#pragma unroll
        for (int h = 0; h < 2; ++h) {
            bf16x8 ka[4], kb2[4];
#pragma unroll
            for (int n = 0; n < 4; ++n) {
                ka[n]  = *(const bf16x8*)(kt + h * 8192 + n * 1024 + lane * 16);
                kb2[n] = *(const bf16x8*)(kt + h * 8192 + 4096 + n * 1024 + lane * 16);
            }
            __builtin_amdgcn_s_setprio(1);
#pragma unroll
            for (int n = 0; n < 4; ++n) {
                s[h * 4 + n] = MFMA16(ka[n], qf0, s[h * 4 + n]);
                s[h * 4 + n] = MFMA16(kb2[n], qf1, s[h * 4 + n]);
            }
            __builtin_amdgcn_s_setprio(0);
        }

        // ---- hoisted V loads (ps = 0,1): latency hides under softmax ----
        bf16x8 vf01[8];
#pragma unroll
        for (int ps = 0; ps < 2; ++ps)
#pragma unroll
            for (int n = 0; n < 4; ++n)
                vf01[ps * 4 + n] = *(const bf16x8*)(vt + (ps & 1) * 4096 + n * 1024 + lane * 16);

        if (t == n2 - 1) {
#pragma unroll
            for (int h = 0; h < 2; ++h)
#pragma unroll
                for (int n = 0; n < 4; ++n) {
                    const int key0 = t * 128 + h * 64 + n * 16 + g * 4;
#pragma unroll
                    for (int r = 0; r < 4; ++r)
                        if (key0 + r > qr0c) s[h * 4 + n][r] = -1e30f;
                }
        }

        float tm = -1e30f;
#pragma unroll
        for (int i = 0; i < 8; ++i)
            tm = fmaxf(tm, fmaxf(fmaxf(s[i][0], s[i][1]), fmaxf(s[i][2], s[i][3])));

        if (__any(tm > m + 8.f)) {
            float gm = tm;
            gm = fmaxf(gm, __shfl_xor(gm, 16, 64));
            gm = fmaxf(gm, __shfl_xor(gm, 32, 64));
            const float mn = fmaxf(m, gm);
            const float alpha = exp2f(m - mn);
            m = mn;
            l *= alpha;
            float al[4];
#pragma unroll
            for (int r = 0; r < 4; ++r) al[r] = __shfl(alpha, g * 4 + r, 16);
#pragma unroll
            for (int n = 0; n < 4; ++n)
#pragma unroll
                for (int r = 0; r < 4; ++r) acc[n][r] *= al[r];
        }

        char* pw = &p_lds[W * 4096 + ((g >> 1) * 16 + c) * 16 + (g & 1) * 8];
#pragma unroll
        for (int h = 0; h < 2; ++h)
#pragma unroll
            for (int n = 0; n < 4; ++n) {
                const int i = h * 4 + n;
                float p0 = exp2f(s[i][0] - m);
                float p1 = exp2f(s[i][1] - m);
                float p2 = exp2f(s[i][2] - m);
                float p3 = exp2f(s[i][3] - m);
                l += (p0 + p1) + (p2 + p3);
                u16x4 pk;
                pk[0] = nbfu(p0); pk[1] = nbfu(p1); pk[2] = nbfu(p2); pk[3] = nbfu(p3);
                *(u16x4*)(pw + (h * 2 + (n >> 1)) * 1024 + (n & 1) * 512) = pk;
            }

        const char* pr = &p_lds[W * 4096 + lane * 16];
        // ps = 0,1 : V already in registers
#pragma unroll
        for (int ps = 0; ps < 2; ++ps) {
            bf16x8 pf = *(const bf16x8*)(pr + ps * 1024);
            __builtin_amdgcn_s_setprio(1);
#pragma unroll
            for (int n = 0; n < 4; ++n)
                acc[n] = MFMA16(pf, vf01[ps * 4 + n], acc[n]);
            __builtin_amdgcn_s_setprio(0);
        }
        // ps = 2,3 : load in place (latency covered by ps 0,1 MFMAs)
#pragma unroll
        for (int ps = 2; ps < 4; ++ps) {
            bf16x8 pf = *(const bf16x8*)(pr + ps * 1024);
            bf16x8 vf[4];
#pragma unroll
            for (int n = 0; n < 4; ++n)
                vf[n] = *(const bf16x8*)(vt + 8192 + (ps & 1) * 4096 + n * 1024 + lane * 16);
            __builtin_amdgcn_s_setprio(1);
#pragma unroll
            for (int n = 0; n < 4; ++n)
                acc[n] = MFMA16(pf, vf[n], acc[n]);
            __builtin_amdgcn_s_setprio(0);
        }
    }

    __syncthreads();
    float* accb = (float*)&p_lds[0];   // [w=4][row=16][col=64] f32 = 16KB

    if (st == 1) {
        l += __shfl_xor(l, 16, 64);
        l += __shfl_xor(l, 32, 64);
        if (g == 0) { mb[w][c] = m; lb[w][c] = l; }
#pragma unroll
        for (int n = 0; n < 4; ++n)
#pragma unroll
            for (int r = 0; r < 4; ++r)
                accb[w * 1024 + (g * 4 + r) * 64 + n * 16 + c] = acc[n][r];
    }
    __syncthreads();

    if (st == 0) {
        l += __shfl_xor(l, 16, 64);
        l += __shfl_xor(l, 32, 64);
        const float m1c = mb[w][c];
        const float l1c = lb[w][c];
        const float mF = fmaxf(m, m1c);
        const float a0 = exp2f(m - mF);                        // set 0 always non-empty
        const float a1 = (m1c > -1e29f) ? exp2f(m1c - mF) : 0.f;
        const float inv = 1.f / (l * a0 + l1c * a1);
        const float s0 = a0 * inv, s1 = a1 * inv;
        float s0r[4], s1r[4];
#pragma unroll
        for (int r = 0; r < 4; ++r) {
            s0r[r] = __shfl(s0, g * 4 + r, 16);
            s1r[r] = __shfl(s1, g * 4 + r, 16);
        }
#pragma unroll
        for (int n = 0; n < 4; ++n)
#pragma unroll
            for (int r = 0; r < 4; ++r) {
                const float a1v = accb[w * 1024 + (g * 4 + r) * 64 + n * 16 + c];
                out[(qrow_g + g * 4 + r) * 64 + n * 16 + c] = acc[n][r] * s0r[r] + a1v * s1r[r];
            }
    }
}

extern "C" void kernel_launch(void* const* d_in, const int* in_sizes, int n_in,
                              void* d_out, int out_size, void* d_ws, size_t ws_size,
                              hipStream_t stream) {
    const float* x1 = (const float*)d_in[0];
    const float* Wq = (const float*)d_in[2];
    const float* Wk = (const float*)d_in[3];
    const float* Wv = (const float*)d_in[4];
    float* out = (float*)d_out;

    unsigned short* Wt  = (unsigned short*)d_ws;
    unsigned short* Qw  = (unsigned short*)((char*)d_ws + 196608);
    unsigned short* Kfw = (unsigned short*)((char*)d_ws + 196608 + 4194304);
    unsigned short* Vfw = (unsigned short*)((char*)d_ws + 196608 + 2 * 4194304);

    wt_kernel<<<dim3(64, 3), 512, 0, stream>>>(Wq, Wk, Wv, Wt);
    qkv_proj<<<256, 512, 0, stream>>>(x1, Wt, Qw, Kfw, Vfw);
    flash_attn<<<512, 512, 0, stream>>>(Qw, Kfw, Vfw, out);
}